// Round 13
// baseline (468.030 us; speedup 1.0000x reference)
//
#include <hip/hip_runtime.h>
#include <hip/hip_bf16.h>
#include <math.h>

#define N_NODES 100000
#define N_EDGES 1600000
#define F 128
#define OUT_C 64
#define NUM_CLASSES 40
#define BN_EPS 1e-5f

#define NBUCK 782   // ceil(100000/128) buckets of 128 destination nodes
#define BCAP 4096   // per-bucket edge capacity

// prep kernel grid roles: weight blocks first (latency-bound, overlap the streams)
#define PREP_WB 0
#define PREP_CONSTB 128
#define PREP_FILLB 129
#define PREP_NFILL 512
#define EPB ((N_EDGES + PREP_NFILL - 1) / PREP_NFILL)  // 3125
#define FILL_ITERS 13                                   // ceil(EPB/256)
#define PREP_CVTB (PREP_FILLB + PREP_NFILL)             // 641
#define CVT8_BLOCKS 3125                                // N_NODES*F/16 / 256

// tiny folded-constant block
#define PSC 0     // [0..127]   BN scale s = rsqrt(var+eps)*gamma
#define POF 128   // [128..255] BN offset o = b1*s + beta - mean*s
#define PFB2 256  // [256..383] fused head bias

typedef __hip_bfloat16 bf16;
typedef __attribute__((ext_vector_type(8))) short bf16x8;
typedef __attribute__((ext_vector_type(4))) float f32x4;

struct ParamSegs {
    const void* src[16];  // [0]=w1 [1]=b1 [2]=w2 [3]=b2 [4]=gamma [5]=beta [6]=mean [7]=var
                          // [8]=cls_w [9]=cls_b [10]=sim_w [11]=sim_b [12]=hom_w [13]=hom_b
                          // [14]=ent_w [15]=ent_b
    int dst[16];
};

__device__ __forceinline__ float uasf(unsigned u) { return __uint_as_float(u); }
__device__ __forceinline__ unsigned f2bu(float f) {
    bf16 h = __float2bfloat16(f);
    return (unsigned)*(unsigned short*)&h;
}
__device__ __forceinline__ float ldp(const void* p, int i, int isf) {
    return isf ? ((const float*)p)[i] : __bfloat162float(((const bf16*)p)[i]);
}
__device__ __forceinline__ int load_edge(const int* __restrict__ ei, int which, int i, int i64) {
    size_t elem = (size_t)which * N_EDGES + (size_t)i;
    return i64 ? ei[elem * 2] : ei[elem];
}
__device__ __forceinline__ int detect_isf(const void* x, int t, int* sflag) {
    if (t < 64) {
        unsigned w = ((const unsigned*)x)[t];
        unsigned e = (w >> 23) & 0xFFu;
        unsigned long long m = __ballot(w == 0u || (e >= 90u && e <= 160u));
        if (t == 0) *sflag = (__popcll(m) >= 48) ? 1 : 0;
    }
    __syncthreads();
    return *sflag;
}
__device__ __forceinline__ int detect_i64(const void* ei, int t, int* sflag) {
    if (t < 64) {
        unsigned long long m = __ballot(((const unsigned*)ei)[2 * t + 1] == 0u);
        if (t == 0) *sflag = (__popcll(m) >= 60) ? 1 : 0;
    }
    __syncthreads();
    return *sflag;
}
__device__ __forceinline__ void head_src(const ParamSegs& segs, int c, const void** hp, int* hb,
                                         int* hs) {
    if (c < OUT_C) {
        *hp = segs.src[8];
        *hb = c;
        *hs = OUT_C;
    } else if (c < OUT_C + NUM_CLASSES) {
        *hp = segs.src[10];
        *hb = c - OUT_C;
        *hs = NUM_CLASSES;
    } else if (c == 104) {
        *hp = segs.src[12];
        *hb = 0;
        *hs = 1;
    } else if (c == 105) {
        *hp = segs.src[14];
        *hb = 0;
        *hs = 1;
    } else {
        *hp = nullptr;
        *hb = 0;
        *hs = 0;
    }
}

// ---- private 8-bit float codec (e4m3-style, no denormals; self-consistent roundtrip) ----
// quant: RNE-ish via +half-ulp (carry-correct), flush |x| < ~2^-6 to 0, clamp to 480.
__device__ __forceinline__ unsigned q8(float f) {
    unsigned b = __float_as_uint(f);
    unsigned s = (b >> 24) & 0x80u;
    unsigned mag = (b & 0x7FFFFFFFu) + 0x00080000u;  // round at mantissa bit 20 (carry ok)
    int e = (int)(mag >> 23) - 127;
    if (e < -6) return s;        // flush to signed zero
    if (e > 8) return s | 0x7Fu; // clamp to max (2^8 * 1.875 = 480)
    return s | ((unsigned)(e + 7) << 3) | ((mag >> 20) & 7u);
}
// dequant: exponent-field add trick; (q&0x7F)==0 -> 0 (quant never emits E=0 nonzero)
__device__ __forceinline__ float dq8(unsigned q) {
    unsigned t = (((q & 0x80u) << 24)) | (((q & 0x7Fu) << 20) + (120u << 23));
    return (q & 0x7Fu) ? uasf(t) : 0.f;
}

#define DQACC(dw, s_, i0)                                            \
    do {                                                             \
        a[(i0) + 0] = fmaf(dq8((dw)&0xFFu), (s_), a[(i0) + 0]);      \
        a[(i0) + 1] = fmaf(dq8(((dw) >> 8) & 0xFFu), (s_), a[(i0) + 1]);  \
        a[(i0) + 2] = fmaf(dq8(((dw) >> 16) & 0xFFu), (s_), a[(i0) + 2]); \
        a[(i0) + 3] = fmaf(dq8((dw) >> 24), (s_), a[(i0) + 3]);      \
    } while (0)
#define DQ16(u, s_)          \
    do {                     \
        DQACC((u).x, s_, 0); \
        DQACC((u).y, s_, 4); \
        DQACC((u).z, s_, 8); \
        DQACC((u).w, s_, 12);\
    } while (0)

// ---------------- prep: weight prep + const fold + edge fill + x -> fp8 ----------------
__global__ __launch_bounds__(256) void prep_kernel(const void* __restrict__ x,
                                                   const int* __restrict__ ei, ParamSegs segs,
                                                   int* __restrict__ bcur,
                                                   int* __restrict__ srcBuck,
                                                   float* __restrict__ params,
                                                   unsigned short* __restrict__ wt,
                                                   unsigned char* __restrict__ X8) {
    __shared__ int sflag;
    int t = threadIdx.x;
    int bid = blockIdx.x;

    if (bid < PREP_CONSTB) {
        // ---- weight prep (hoisted head source) ----
        int isf = detect_isf(x, t, &sflag);
        int idx = bid * 256 + t;  // 0..32767
        if (idx < 16384) {
            int kf = idx >> 7, c = idx & 127;
            const void* hp;
            int hb, hs;
            head_src(segs, c, &hp, &hb, &hs);
            float s = 0.f;
            if (hp) {
                const void* w2 = segs.src[2];
#pragma unroll 8
                for (int j = 0; j < 128; j++)
                    s += ldp(w2, kf * 128 + j, isf) * ldp(hp, j * hs + hb, isf);
            }
            int p = (kf & 15) * 8 + (kf >> 4);
            wt[16384 + c * 128 + p] = (unsigned short)f2bu(s);
        } else {
            int l = idx - 16384;
            int n = l >> 7, k = l & 127;
            wt[n * 128 + k] = (unsigned short)f2bu(ldp(segs.src[0], k * 128 + n, isf));
        }
    } else if (bid == PREP_CONSTB) {
        int isf = detect_isf(x, t, &sflag);
        if (t < 128) {
            float s = rsqrtf(ldp(segs.src[7], t, isf) + BN_EPS) * ldp(segs.src[4], t, isf);
            params[PSC + t] = s;
            params[POF + t] = ldp(segs.src[1], t, isf) * s + ldp(segs.src[5], t, isf) -
                              ldp(segs.src[6], t, isf) * s;
            const void* hp;
            int hb, hs;
            head_src(segs, t, &hp, &hb, &hs);
            float b = 0.f;
            if (hp) {
                const void* b2 = segs.src[3];
#pragma unroll 8
                for (int j = 0; j < 128; j++) b += ldp(b2, j, isf) * ldp(hp, j * hs + hb, isf);
            }
            if (t < OUT_C) b += ldp(segs.src[9], t, isf);
            else if (t < OUT_C + NUM_CLASSES) b += ldp(segs.src[11], t - OUT_C, isf);
            else if (t == 104) b += ldp(segs.src[13], 0, isf);
            else if (t == 105) b += ldp(segs.src[15], 0, isf);
            params[PFB2 + t] = b;
        }
    } else if (bid < PREP_CVTB) {
        // ---- edge fill ----
        __shared__ int hist[NBUCK];
        __shared__ int gbase[NBUCK];
        __shared__ int lcur[NBUCK];
        int i64 = detect_i64(ei, t, &sflag);
        int blk = bid - PREP_FILLB;
        int e0 = blk * EPB;
        int ecnt = N_EDGES - e0;
        if (ecnt > EPB) ecnt = EPB;
        for (int i = t; i < NBUCK; i += 256) hist[i] = 0;
        __syncthreads();
        int ccache[FILL_ITERS];
#pragma unroll
        for (int it = 0; it < FILL_ITERS; ++it) {
            int i = t + it * 256;
            int c = -1;
            if (i < ecnt) {
                c = load_edge(ei, 1, e0 + i, i64);
                atomicAdd(&hist[c >> 7], 1);
            }
            ccache[it] = c;
        }
        __syncthreads();
        for (int i = t; i < NBUCK; i += 256) {
            int c = hist[i];
            gbase[i] = (c > 0) ? atomicAdd(&bcur[i], c) : 0;
            lcur[i] = 0;
        }
        __syncthreads();
#pragma unroll
        for (int it = 0; it < FILL_ITERS; ++it) {
            int i = t + it * 256;
            if (i < ecnt) {
                int c = ccache[it];
                int r = load_edge(ei, 0, e0 + i, i64);
                int b = c >> 7;
                int p = gbase[b] + atomicAdd(&lcur[b], 1);
                if (p < BCAP) srcBuck[b * BCAP + p] = ((c & 127) << 17) | r;
            }
        }
    } else {
        // ---- x -> fp8 (full rows become single 128B cache lines) ----
        int isf = detect_isf(x, t, &sflag);
        int i16 = (bid - PREP_CVTB) * 256 + t;  // exactly 800000 items of 16 values
        unsigned o0, o1, o2, o3;
        if (isf) {
            const float* xf = (const float*)x + (size_t)i16 * 16;
            float4 v0 = *(const float4*)(xf + 0);
            float4 v1 = *(const float4*)(xf + 4);
            float4 v2 = *(const float4*)(xf + 8);
            float4 v3 = *(const float4*)(xf + 12);
            o0 = q8(v0.x) | (q8(v0.y) << 8) | (q8(v0.z) << 16) | (q8(v0.w) << 24);
            o1 = q8(v1.x) | (q8(v1.y) << 8) | (q8(v1.z) << 16) | (q8(v1.w) << 24);
            o2 = q8(v2.x) | (q8(v2.y) << 8) | (q8(v2.z) << 16) | (q8(v2.w) << 24);
            o3 = q8(v3.x) | (q8(v3.y) << 8) | (q8(v3.z) << 16) | (q8(v3.w) << 24);
        } else {
            const uint4* xu = (const uint4*)((const unsigned short*)x + (size_t)i16 * 16);
            uint4 u0 = xu[0], u1 = xu[1];
            o0 = q8(uasf(u0.x << 16)) | (q8(uasf(u0.x & 0xFFFF0000u)) << 8) |
                 (q8(uasf(u0.y << 16)) << 16) | (q8(uasf(u0.y & 0xFFFF0000u)) << 24);
            o1 = q8(uasf(u0.z << 16)) | (q8(uasf(u0.z & 0xFFFF0000u)) << 8) |
                 (q8(uasf(u0.w << 16)) << 16) | (q8(uasf(u0.w & 0xFFFF0000u)) << 24);
            o2 = q8(uasf(u1.x << 16)) | (q8(uasf(u1.x & 0xFFFF0000u)) << 8) |
                 (q8(uasf(u1.y << 16)) << 16) | (q8(uasf(u1.y & 0xFFFF0000u)) << 24);
            o3 = q8(uasf(u1.z << 16)) | (q8(uasf(u1.z & 0xFFFF0000u)) << 8) |
                 (q8(uasf(u1.w << 16)) << 16) | (q8(uasf(u1.w & 0xFFFF0000u)) << 24);
        }
        ((uint4*)X8)[i16] = make_uint4(o0, o1, o2, o3);
    }
}

// ---------------- presort: one-time LDS counting sort per bucket, in-place ----------------
__global__ __launch_bounds__(512) void presort_kernel(int* __restrict__ srcBuck,
                                                      const int* __restrict__ bcur,
                                                      int* __restrict__ doffG,
                                                      int* __restrict__ dcntG,
                                                      float* __restrict__ dinv) {
    __shared__ int raw[BCAP];
    __shared__ int sorted[BCAP];
    __shared__ int dcnt[128], doff[128], dcur[128];
    int b = blockIdx.x;
    int t = threadIdx.x;
    int cnt = bcur[b];
    if (cnt > BCAP) cnt = BCAP;
    if (t < 128) dcnt[t] = 0;
    __syncthreads();
    for (int i = t; i < cnt; i += 512) {
        int e = srcBuck[b * BCAP + i];
        raw[i] = e;
        atomicAdd(&dcnt[e >> 17], 1);
    }
    __syncthreads();
    if (t < 128) doff[t] = dcnt[t];
    __syncthreads();
    for (int d = 1; d < 128; d <<= 1) {
        int add = 0;
        if (t < 128 && t >= d) add = doff[t - d];
        __syncthreads();
        if (t < 128) doff[t] += add;
        __syncthreads();
    }
    if (t < 128) {
        doff[t] -= dcnt[t];
        dcur[t] = 0;
    }
    __syncthreads();
    for (int i = t; i < cnt; i += 512) {
        int e = raw[i];
        int d = e >> 17;
        int r = atomicAdd(&dcur[d], 1);
        sorted[doff[d] + r] = e & 0x1FFFF;
    }
    __syncthreads();
    for (int i = t; i < cnt; i += 512) srcBuck[b * BCAP + i] = sorted[i];
    if (t < 128) {
        doffG[(b << 7) + t] = doff[t];
        dcntG[(b << 7) + t] = dcnt[t];
        int n = (b << 7) + t;
        if (n < N_NODES) dinv[n] = rsqrtf((float)(dcnt[t] + 1));
    }
}

// ---------------- fp8 full-row aggregation: one bucket per block, no XCD split ------------
// fp8 rows are 128B = exactly one cache line -> per-XCD compulsory fill halves to 12.8MB
// (total FETCH ~115MB vs 166) with NO half-split: simpler grid (bucket<->block direct),
// srcBuck read once, no claim/steal. SRC1: inline dinv[src] scale (layer 1, X8 input);
// !SRC1: plain sum (layer 2, H8 input; h1 prescaled by gemm1 epilogue).
template <bool SRC1>
__global__ __launch_bounds__(512) void aggf8_kernel(const unsigned char* __restrict__ IN8,
                                                    unsigned short* __restrict__ OUT16,
                                                    const int* __restrict__ srcBuck,
                                                    const int* __restrict__ doffG,
                                                    const int* __restrict__ dcntG,
                                                    const float* __restrict__ dinv) {
    __shared__ int sIdx[BCAP];
    __shared__ int sdoff[128], sdcnt[128];
    int t = threadIdx.x;
    int b = blockIdx.x;
    if (t < 128) {
        sdoff[t] = doffG[(b << 7) + t];
        sdcnt[t] = dcntG[(b << 7) + t];
    }
    __syncthreads();
    int cnt = sdoff[127] + sdcnt[127];
    for (int i = t; i < cnt; i += 512) sIdx[i] = srcBuck[b * BCAP + i];
    __syncthreads();

    int g8 = t >> 3;             // 64 groups of 8 lanes; each group owns dests g8, g8+64
    int boff = (t & 7) << 4;     // 16 features (bytes) per lane within the 128B row
    int base = b << 7;
    for (int d = g8; d < 128; d += 64) {
        int n = base + d;
        if (n >= N_NODES) break;
        float dn = dinv[n];
        float a[16];
#pragma unroll
        for (int i = 0; i < 16; i++) a[i] = 0.f;
        {
            uint4 u = *(const uint4*)(IN8 + (size_t)n * 128 + boff);
            if (SRC1) DQ16(u, dn);
            else DQ16(u, 1.0f);
        }
        int o = sdoff[d], k = sdcnt[d];
        int j = 0;
        for (; j + 8 <= k; j += 8) {
            int s0 = sIdx[o + j + 0], s1 = sIdx[o + j + 1];
            int s2 = sIdx[o + j + 2], s3 = sIdx[o + j + 3];
            int s4 = sIdx[o + j + 4], s5 = sIdx[o + j + 5];
            int s6 = sIdx[o + j + 6], s7 = sIdx[o + j + 7];
            uint4 u0 = *(const uint4*)(IN8 + (size_t)s0 * 128 + boff);
            uint4 u1 = *(const uint4*)(IN8 + (size_t)s1 * 128 + boff);
            uint4 u2 = *(const uint4*)(IN8 + (size_t)s2 * 128 + boff);
            uint4 u3 = *(const uint4*)(IN8 + (size_t)s3 * 128 + boff);
            uint4 u4 = *(const uint4*)(IN8 + (size_t)s4 * 128 + boff);
            uint4 u5 = *(const uint4*)(IN8 + (size_t)s5 * 128 + boff);
            uint4 u6 = *(const uint4*)(IN8 + (size_t)s6 * 128 + boff);
            uint4 u7 = *(const uint4*)(IN8 + (size_t)s7 * 128 + boff);
            if (SRC1) {
                float f0 = dinv[s0], f1 = dinv[s1], f2 = dinv[s2], f3 = dinv[s3];
                float f4 = dinv[s4], f5 = dinv[s5], f6 = dinv[s6], f7 = dinv[s7];
                DQ16(u0, f0);
                DQ16(u1, f1);
                DQ16(u2, f2);
                DQ16(u3, f3);
                DQ16(u4, f4);
                DQ16(u5, f5);
                DQ16(u6, f6);
                DQ16(u7, f7);
            } else {
                DQ16(u0, 1.0f);
                DQ16(u1, 1.0f);
                DQ16(u2, 1.0f);
                DQ16(u3, 1.0f);
                DQ16(u4, 1.0f);
                DQ16(u5, 1.0f);
                DQ16(u6, 1.0f);
                DQ16(u7, 1.0f);
            }
        }
        for (; j + 4 <= k; j += 4) {
            int s0 = sIdx[o + j + 0], s1 = sIdx[o + j + 1];
            int s2 = sIdx[o + j + 2], s3 = sIdx[o + j + 3];
            uint4 u0 = *(const uint4*)(IN8 + (size_t)s0 * 128 + boff);
            uint4 u1 = *(const uint4*)(IN8 + (size_t)s1 * 128 + boff);
            uint4 u2 = *(const uint4*)(IN8 + (size_t)s2 * 128 + boff);
            uint4 u3 = *(const uint4*)(IN8 + (size_t)s3 * 128 + boff);
            if (SRC1) {
                float f0 = dinv[s0], f1 = dinv[s1], f2 = dinv[s2], f3 = dinv[s3];
                DQ16(u0, f0);
                DQ16(u1, f1);
                DQ16(u2, f2);
                DQ16(u3, f3);
            } else {
                DQ16(u0, 1.0f);
                DQ16(u1, 1.0f);
                DQ16(u2, 1.0f);
                DQ16(u3, 1.0f);
            }
        }
        for (; j < k; j++) {
            int s0 = sIdx[o + j];
            uint4 u0 = *(const uint4*)(IN8 + (size_t)s0 * 128 + boff);
            if (SRC1) {
                float f0 = dinv[s0];
                DQ16(u0, f0);
            } else {
                DQ16(u0, 1.0f);
            }
        }
        // write 16 bf16 (32B) at natural feature order for the MFMA A-operand
        uint4 p0, p1;
        p0.x = f2bu(a[0] * dn) | (f2bu(a[1] * dn) << 16);
        p0.y = f2bu(a[2] * dn) | (f2bu(a[3] * dn) << 16);
        p0.z = f2bu(a[4] * dn) | (f2bu(a[5] * dn) << 16);
        p0.w = f2bu(a[6] * dn) | (f2bu(a[7] * dn) << 16);
        p1.x = f2bu(a[8] * dn) | (f2bu(a[9] * dn) << 16);
        p1.y = f2bu(a[10] * dn) | (f2bu(a[11] * dn) << 16);
        p1.z = f2bu(a[12] * dn) | (f2bu(a[13] * dn) << 16);
        p1.w = f2bu(a[14] * dn) | (f2bu(a[15] * dn) << 16);
        unsigned short* wp = OUT16 + (size_t)n * 128 + boff;
        *(uint4*)wp = p0;
        *(uint4*)(wp + 8) = p1;
    }
}

// ---------------- MFMA GEMM; mode1 packs h1 as fp8 (halves layer-2 gather array) ----------
__global__ __launch_bounds__(256) void gemm_mfma_kernel(
    const unsigned short* __restrict__ A16, const unsigned short* __restrict__ Wt,
    unsigned char* __restrict__ outB8, void* __restrict__ out,
    const float* __restrict__ params, const float* __restrict__ dinv, int mode,
    const void* __restrict__ x) {
    __shared__ float sF1[128], sF2[128];
    __shared__ int sflag;
    int t = threadIdx.x;
    int isf = detect_isf(x, t, &sflag);
    if (t < 128) {
        if (mode) {
            sF1[t] = params[PSC + t];
            sF2[t] = params[POF + t];
        } else {
            sF1[t] = params[PFB2 + t];
        }
    }
    __syncthreads();
    int wave = t >> 6, lane = t & 63, m16 = lane & 15, quad = lane >> 4;
    int rowbase = blockIdx.x * 64 + wave * 16;
    int rA = rowbase + m16;
    if (rA >= N_NODES) rA = N_NODES - 1;
    const size_t abase = (size_t)rA * 128 + (quad << 3);

    f32x4 acc[8];
#pragma unroll
    for (int ct = 0; ct < 8; ct++) acc[ct] = (f32x4){0.f, 0.f, 0.f, 0.f};
#pragma unroll
    for (int kk = 0; kk < 4; kk++) {
        bf16x8 af = *(const bf16x8*)(A16 + abase + kk * 32);
#pragma unroll
        for (int ct = 0; ct < 8; ct++) {
            bf16x8 bfr = *(const bf16x8*)(Wt + (size_t)((ct * 16 + m16) * 128) + kk * 32 + (quad << 3));
            acc[ct] = __builtin_amdgcn_mfma_f32_16x16x32_bf16(af, bfr, acc[ct], 0, 0, 0);
        }
    }

    int r0 = rowbase + quad * 4;
    if (mode) {
        float sc[8], of[8];
#pragma unroll
        for (int ct = 0; ct < 8; ct++) {
            sc[ct] = sF1[ct * 16 + m16];
            of[ct] = sF2[ct * 16 + m16];
        }
#pragma unroll
        for (int reg = 0; reg < 4; reg++) {
            int gr = r0 + reg;
            if (gr >= N_NODES) continue;
            float dn = dinv[gr];
            float vv[8];
#pragma unroll
            for (int ct = 0; ct < 8; ct++)
                vv[ct] = fmaxf(acc[ct][reg] * sc[ct] + of[ct], 0.f) * dn;
            unsigned lo = q8(vv[0]) | (q8(vv[1]) << 8) | (q8(vv[2]) << 16) | (q8(vv[3]) << 24);
            unsigned hi = q8(vv[4]) | (q8(vv[5]) << 8) | (q8(vv[6]) << 16) | (q8(vv[7]) << 24);
            *(uint2*)(outB8 + (size_t)gr * 128 + (m16 << 3)) = make_uint2(lo, hi);
        }
    } else {
        const size_t OFF_SIM = (size_t)N_NODES * OUT_C;
        const size_t OFF_HOM = OFF_SIM + (size_t)N_NODES * NUM_CLASSES;
        const size_t OFF_ENT = OFF_HOM + (size_t)N_NODES;
        float* outf = (float*)out;
        bf16* outb = (bf16*)out;
        float fb[8];
#pragma unroll
        for (int ct = 0; ct < 8; ct++) fb[ct] = sF1[ct * 16 + m16];
#define STORE_OUT(idx, v)                        \
    do {                                         \
        if (isf) outf[(idx)] = (v);              \
        else outb[(idx)] = __float2bfloat16(v);  \
    } while (0)
#pragma unroll
        for (int reg = 0; reg < 4; reg++) {
            int gr = r0 + reg;
            bool vrow = (gr < N_NODES);
            float v[8];
#pragma unroll
            for (int ct = 0; ct < 8; ct++) v[ct] = acc[ct][reg] + fb[ct];
            float m = fmaxf(fmaxf(v[0], v[1]), fmaxf(v[2], v[3]));
            m = fmaxf(m, __shfl_xor(m, 1));
            m = fmaxf(m, __shfl_xor(m, 2));
            m = fmaxf(m, __shfl_xor(m, 4));
            m = fmaxf(m, __shfl_xor(m, 8));
            float S = __expf(v[0] - m) + __expf(v[1] - m) + __expf(v[2] - m) + __expf(v[3] - m);
            S += __shfl_xor(S, 1);
            S += __shfl_xor(S, 2);
            S += __shfl_xor(S, 4);
            S += __shfl_xor(S, 8);
            float lS = m + __logf(S);
            if (vrow) {
#pragma unroll
                for (int ct = 0; ct < 4; ct++)
                    STORE_OUT((size_t)gr * OUT_C + ct * 16 + m16, v[ct] - lS);
            }
            bool has6 = (m16 < 8);
            float s4 = v[4], s5 = v[5], s6 = has6 ? v[6] : -INFINITY;
            float m2 = fmaxf(fmaxf(s4, s5), s6);
            m2 = fmaxf(m2, __shfl_xor(m2, 1));
            m2 = fmaxf(m2, __shfl_xor(m2, 2));
            m2 = fmaxf(m2, __shfl_xor(m2, 4));
            m2 = fmaxf(m2, __shfl_xor(m2, 8));
            float e4 = __expf(s4 - m2), e5 = __expf(s5 - m2), e6 = has6 ? __expf(s6 - m2) : 0.f;
            float S2 = e4 + e5 + e6;
            S2 += __shfl_xor(S2, 1);
            S2 += __shfl_xor(S2, 2);
            S2 += __shfl_xor(S2, 4);
            S2 += __shfl_xor(S2, 8);
            float rS2 = 1.f / S2;
            if (vrow) {
                STORE_OUT(OFF_SIM + (size_t)gr * NUM_CLASSES + m16, e4 * rS2);
                STORE_OUT(OFF_SIM + (size_t)gr * NUM_CLASSES + 16 + m16, e5 * rS2);
                if (has6) STORE_OUT(OFF_SIM + (size_t)gr * NUM_CLASSES + 32 + m16, e6 * rS2);
                if (m16 == 8) STORE_OUT(OFF_HOM + gr, 1.f / (1.f + __expf(-v[6])));
                if (m16 == 9) STORE_OUT(OFF_ENT + gr, 1.f / (1.f + __expf(-v[6])));
            }
        }
#undef STORE_OUT
    }
}

// ---------------- Launch: memset + 6 kernels ----------------
extern "C" void kernel_launch(void* const* d_in, const int* in_sizes, int n_in,
                              void* d_out, int out_size, void* d_ws, size_t ws_size,
                              hipStream_t stream) {
    const void* x = d_in[0];
    const int* ei = (const int*)d_in[1];

    char* ws = (char*)d_ws;
    size_t o = 0;
    auto alloc = [&](size_t bytes) {
        size_t r = o;
        o = (o + bytes + 255) & ~(size_t)255;
        return r;
    };
    char* RA = ws + alloc((size_t)51 * 1024 * 1024);  // srcBuck + X8 + H8
    char* RB = ws + alloc((size_t)26 * 1024 * 1024);  // G16
    float* params = (float*)(ws + alloc(2048));
    unsigned short* wt = (unsigned short*)(ws + alloc(65536));
    float* dinv = (float*)(ws + alloc((size_t)N_NODES * 4));
    int* doffG = (int*)(ws + alloc((size_t)NBUCK * 128 * 4));
    int* dcntG = (int*)(ws + alloc((size_t)NBUCK * 128 * 4));
    int* bcur = (int*)(ws + alloc((size_t)(NBUCK + 8) * 4));

    int* srcBuck = (int*)RA;                                        // 12.81 MB
    unsigned char* X8 = (unsigned char*)(RA + 13u * 1024 * 1024);   // 12.8 MB (fp8 x)
    unsigned char* H8 = (unsigned char*)(RA + 26u * 1024 * 1024);   // 12.8 MB (fp8 h1)
    unsigned short* G16 = (unsigned short*)RB;                      // 25.6 MB (g, bf16)

    hipMemsetAsync(bcur, 0, (size_t)(NBUCK + 8) * 4, stream);

    ParamSegs segs;
    const int srcIdx[16] = {2, 3, 4, 5, 6, 7, 8, 9, 10, 11, 12, 13, 14, 15, 16, 17};
    for (int k = 0; k < 16; k++) {
        segs.src[k] = d_in[srcIdx[k]];
        segs.dst[k] = 0;
    }

    prep_kernel<<<PREP_CVTB + CVT8_BLOCKS, 256, 0, stream>>>(x, ei, segs, bcur, srcBuck, params,
                                                             wt, X8);
    presort_kernel<<<NBUCK, 512, 0, stream>>>(srcBuck, bcur, doffG, dcntG, dinv);

    const int gemmGrid = (N_NODES + 63) / 64;
    // layer 1: g1 = A_hat x  (fp8 full-row gather, dinv[src] inline) -> G16 (bf16)
    aggf8_kernel<true><<<NBUCK, 512, 0, stream>>>(X8, G16, srcBuck, doffG, dcntG, dinv);
    // h1 = fp8(ReLU(BN(g1 W1 + b1)) * dinv) -> H8
    gemm_mfma_kernel<<<gemmGrid, 256, 0, stream>>>(G16, wt, H8, nullptr, params, dinv, 1, x);
    // layer 2: g2 = A_hat h1 (fp8 gather, plain sum) -> G16
    aggf8_kernel<false><<<NBUCK, 512, 0, stream>>>(H8, G16, srcBuck, doffG, dcntG, dinv);
    // heads
    gemm_mfma_kernel<<<gemmGrid, 256, 0, stream>>>(G16, wt + 16384, nullptr, d_out, params, dinv,
                                                   0, x);
}

// Round 14
// 397.794 us; speedup vs baseline: 1.1766x; 1.1766x over previous
//
#include <hip/hip_runtime.h>
#include <hip/hip_bf16.h>
#include <math.h>

#define N_NODES 100000
#define N_EDGES 1600000
#define F 128
#define OUT_C 64
#define NUM_CLASSES 40
#define BN_EPS 1e-5f

#define NBUCK 782   // ceil(100000/128) buckets of 128 destination nodes
#define BCAP 4096   // per-bucket edge capacity

// prep kernel grid roles: weight blocks first (latency-bound, overlap the streams)
#define PREP_CONSTB 128
#define PREP_FILLB 129
#define PREP_NFILL 512
#define EPB ((N_EDGES + PREP_NFILL - 1) / PREP_NFILL)  // 3125
#define FILL_ITERS 13                                   // ceil(EPB/256)
#define PREP_CVTB (PREP_FILLB + PREP_NFILL)             // 641
#define CVT8_BLOCKS 3125                                // N_NODES*F/16 / 256

// tiny folded-constant block
#define PSC 0     // [0..127]   BN scale s = rsqrt(var+eps)*gamma
#define POF 128   // [128..255] BN offset o = b1*s + beta - mean*s
#define PFB2 256  // [256..383] fused head bias

#define EXPFIX 0x1p120f  // folds the fp8 exponent bias (see dq8r)

typedef __hip_bfloat16 bf16;
typedef __attribute__((ext_vector_type(8))) short bf16x8;
typedef __attribute__((ext_vector_type(4))) float f32x4;

struct ParamSegs {
    const void* src[16];  // [0]=w1 [1]=b1 [2]=w2 [3]=b2 [4]=gamma [5]=beta [6]=mean [7]=var
                          // [8]=cls_w [9]=cls_b [10]=sim_w [11]=sim_b [12]=hom_w [13]=hom_b
                          // [14]=ent_w [15]=ent_b
    int dst[16];
};

__device__ __forceinline__ float uasf(unsigned u) { return __uint_as_float(u); }
__device__ __forceinline__ unsigned f2bu(float f) {
    bf16 h = __float2bfloat16(f);
    return (unsigned)*(unsigned short*)&h;
}
__device__ __forceinline__ float ldp(const void* p, int i, int isf) {
    return isf ? ((const float*)p)[i] : __bfloat162float(((const bf16*)p)[i]);
}
__device__ __forceinline__ int load_edge(const int* __restrict__ ei, int which, int i, int i64) {
    size_t elem = (size_t)which * N_EDGES + (size_t)i;
    return i64 ? ei[elem * 2] : ei[elem];
}
__device__ __forceinline__ int detect_isf(const void* x, int t, int* sflag) {
    if (t < 64) {
        unsigned w = ((const unsigned*)x)[t];
        unsigned e = (w >> 23) & 0xFFu;
        unsigned long long m = __ballot(w == 0u || (e >= 90u && e <= 160u));
        if (t == 0) *sflag = (__popcll(m) >= 48) ? 1 : 0;
    }
    __syncthreads();
    return *sflag;
}
__device__ __forceinline__ int detect_i64(const void* ei, int t, int* sflag) {
    if (t < 64) {
        unsigned long long m = __ballot(((const unsigned*)ei)[2 * t + 1] == 0u);
        if (t == 0) *sflag = (__popcll(m) >= 60) ? 1 : 0;
    }
    __syncthreads();
    return *sflag;
}
__device__ __forceinline__ void head_src(const ParamSegs& segs, int c, const void** hp, int* hb,
                                         int* hs) {
    if (c < OUT_C) {
        *hp = segs.src[8];
        *hb = c;
        *hs = OUT_C;
    } else if (c < OUT_C + NUM_CLASSES) {
        *hp = segs.src[10];
        *hb = c - OUT_C;
        *hs = NUM_CLASSES;
    } else if (c == 104) {
        *hp = segs.src[12];
        *hb = 0;
        *hs = 1;
    } else if (c == 105) {
        *hp = segs.src[14];
        *hb = 0;
        *hs = 1;
    } else {
        *hp = nullptr;
        *hb = 0;
        *hs = 0;
    }
}

// ---- private 8-bit float codec (e4m3-style, bias 7; no denormals) ----
// quant: RNE-ish via +half-ulp (carry-correct), flush |x| < ~2^-6 to 0, clamp to 480.
__device__ __forceinline__ unsigned q8(float f) {
    unsigned b = __float_as_uint(f);
    unsigned s = (b >> 24) & 0x80u;
    unsigned mag = (b & 0x7FFFFFFFu) + 0x00080000u;  // round at mantissa bit 20 (carry ok)
    int e = (int)(mag >> 23) - 127;
    if (e < -6) return s;        // flush to signed zero
    if (e > 8) return s | 0x7Fu; // clamp to max (2^8 * 1.875 = 480)
    return s | ((unsigned)(e + 7) << 3) | ((mag >> 20) & 7u);
}
// RAW dequant: place E|M at exponent/mantissa field (value = true * 2^-120), sign at 31.
// Consumers fold 2^120 into the fma scale (EXPFIX). E=0,M=0 -> +-0 naturally.
__device__ __forceinline__ float dq8r(unsigned wm, unsigned ws) {
    return uasf((wm & 0x07F00000u) | (ws & 0x80000000u));
}

// 4 values from one dword; scale s_ must carry EXPFIX. ~4-5 VALU/value (2 shl + and_or + fma).
#define DQACC(dw, s_, i0)                                              \
    do {                                                               \
        a[(i0) + 0] = fmaf(dq8r((dw) << 20, (dw) << 24), (s_), a[(i0) + 0]); \
        a[(i0) + 1] = fmaf(dq8r((dw) << 12, (dw) << 16), (s_), a[(i0) + 1]); \
        a[(i0) + 2] = fmaf(dq8r((dw) << 4, (dw) << 8), (s_), a[(i0) + 2]);   \
        a[(i0) + 3] = fmaf(dq8r((dw) >> 4, (dw)), (s_), a[(i0) + 3]);        \
    } while (0)
#define DQ16(u, s_)           \
    do {                      \
        DQACC((u).x, s_, 0);  \
        DQACC((u).y, s_, 4);  \
        DQACC((u).z, s_, 8);  \
        DQACC((u).w, s_, 12); \
    } while (0)

// ---------------- prep: weight prep + const fold + edge fill + x -> fp8 ----------------
__global__ __launch_bounds__(256) void prep_kernel(const void* __restrict__ x,
                                                   const int* __restrict__ ei, ParamSegs segs,
                                                   int* __restrict__ bcur,
                                                   int* __restrict__ srcBuck,
                                                   float* __restrict__ params,
                                                   unsigned short* __restrict__ wt,
                                                   unsigned char* __restrict__ X8) {
    __shared__ int sflag;
    int t = threadIdx.x;
    int bid = blockIdx.x;

    if (bid < PREP_CONSTB) {
        int isf = detect_isf(x, t, &sflag);
        int idx = bid * 256 + t;  // 0..32767
        if (idx < 16384) {
            int kf = idx >> 7, c = idx & 127;
            const void* hp;
            int hb, hs;
            head_src(segs, c, &hp, &hb, &hs);
            float s = 0.f;
            if (hp) {
                const void* w2 = segs.src[2];
#pragma unroll 8
                for (int j = 0; j < 128; j++)
                    s += ldp(w2, kf * 128 + j, isf) * ldp(hp, j * hs + hb, isf);
            }
            int p = (kf & 15) * 8 + (kf >> 4);
            wt[16384 + c * 128 + p] = (unsigned short)f2bu(s);
        } else {
            int l = idx - 16384;
            int n = l >> 7, k = l & 127;
            wt[n * 128 + k] = (unsigned short)f2bu(ldp(segs.src[0], k * 128 + n, isf));
        }
    } else if (bid == PREP_CONSTB) {
        int isf = detect_isf(x, t, &sflag);
        if (t < 128) {
            float s = rsqrtf(ldp(segs.src[7], t, isf) + BN_EPS) * ldp(segs.src[4], t, isf);
            params[PSC + t] = s;
            params[POF + t] = ldp(segs.src[1], t, isf) * s + ldp(segs.src[5], t, isf) -
                              ldp(segs.src[6], t, isf) * s;
            const void* hp;
            int hb, hs;
            head_src(segs, t, &hp, &hb, &hs);
            float b = 0.f;
            if (hp) {
                const void* b2 = segs.src[3];
#pragma unroll 8
                for (int j = 0; j < 128; j++) b += ldp(b2, j, isf) * ldp(hp, j * hs + hb, isf);
            }
            if (t < OUT_C) b += ldp(segs.src[9], t, isf);
            else if (t < OUT_C + NUM_CLASSES) b += ldp(segs.src[11], t - OUT_C, isf);
            else if (t == 104) b += ldp(segs.src[13], 0, isf);
            else if (t == 105) b += ldp(segs.src[15], 0, isf);
            params[PFB2 + t] = b;
        }
    } else if (bid < PREP_CVTB) {
        // ---- edge fill ----
        __shared__ int hist[NBUCK];
        __shared__ int gbase[NBUCK];
        __shared__ int lcur[NBUCK];
        int i64 = detect_i64(ei, t, &sflag);
        int blk = bid - PREP_FILLB;
        int e0 = blk * EPB;
        int ecnt = N_EDGES - e0;
        if (ecnt > EPB) ecnt = EPB;
        for (int i = t; i < NBUCK; i += 256) hist[i] = 0;
        __syncthreads();
        int ccache[FILL_ITERS];
#pragma unroll
        for (int it = 0; it < FILL_ITERS; ++it) {
            int i = t + it * 256;
            int c = -1;
            if (i < ecnt) {
                c = load_edge(ei, 1, e0 + i, i64);
                atomicAdd(&hist[c >> 7], 1);
            }
            ccache[it] = c;
        }
        __syncthreads();
        for (int i = t; i < NBUCK; i += 256) {
            int c = hist[i];
            gbase[i] = (c > 0) ? atomicAdd(&bcur[i], c) : 0;
            lcur[i] = 0;
        }
        __syncthreads();
#pragma unroll
        for (int it = 0; it < FILL_ITERS; ++it) {
            int i = t + it * 256;
            if (i < ecnt) {
                int c = ccache[it];
                int r = load_edge(ei, 0, e0 + i, i64);
                int b = c >> 7;
                int p = gbase[b] + atomicAdd(&lcur[b], 1);
                if (p < BCAP) srcBuck[b * BCAP + p] = ((c & 127) << 17) | r;
            }
        }
    } else {
        // ---- x -> fp8 (full rows become single 128B cache lines) ----
        int isf = detect_isf(x, t, &sflag);
        int i16 = (bid - PREP_CVTB) * 256 + t;  // exactly 800000 items of 16 values
        unsigned o0, o1, o2, o3;
        if (isf) {
            const float* xf = (const float*)x + (size_t)i16 * 16;
            float4 v0 = *(const float4*)(xf + 0);
            float4 v1 = *(const float4*)(xf + 4);
            float4 v2 = *(const float4*)(xf + 8);
            float4 v3 = *(const float4*)(xf + 12);
            o0 = q8(v0.x) | (q8(v0.y) << 8) | (q8(v0.z) << 16) | (q8(v0.w) << 24);
            o1 = q8(v1.x) | (q8(v1.y) << 8) | (q8(v1.z) << 16) | (q8(v1.w) << 24);
            o2 = q8(v2.x) | (q8(v2.y) << 8) | (q8(v2.z) << 16) | (q8(v2.w) << 24);
            o3 = q8(v3.x) | (q8(v3.y) << 8) | (q8(v3.z) << 16) | (q8(v3.w) << 24);
        } else {
            const uint4* xu = (const uint4*)((const unsigned short*)x + (size_t)i16 * 16);
            uint4 u0 = xu[0], u1 = xu[1];
            o0 = q8(uasf(u0.x << 16)) | (q8(uasf(u0.x & 0xFFFF0000u)) << 8) |
                 (q8(uasf(u0.y << 16)) << 16) | (q8(uasf(u0.y & 0xFFFF0000u)) << 24);
            o1 = q8(uasf(u0.z << 16)) | (q8(uasf(u0.z & 0xFFFF0000u)) << 8) |
                 (q8(uasf(u0.w << 16)) << 16) | (q8(uasf(u0.w & 0xFFFF0000u)) << 24);
            o2 = q8(uasf(u1.x << 16)) | (q8(uasf(u1.x & 0xFFFF0000u)) << 8) |
                 (q8(uasf(u1.y << 16)) << 16) | (q8(uasf(u1.y & 0xFFFF0000u)) << 24);
            o3 = q8(uasf(u1.z << 16)) | (q8(uasf(u1.z & 0xFFFF0000u)) << 8) |
                 (q8(uasf(u1.w << 16)) << 16) | (q8(uasf(u1.w & 0xFFFF0000u)) << 24);
        }
        ((uint4*)X8)[i16] = make_uint4(o0, o1, o2, o3);
    }
}

// ---------------- presort: one-time LDS counting sort per bucket, in-place ----------------
__global__ __launch_bounds__(512) void presort_kernel(int* __restrict__ srcBuck,
                                                      const int* __restrict__ bcur,
                                                      int* __restrict__ doffG,
                                                      int* __restrict__ dcntG,
                                                      float* __restrict__ dinv) {
    __shared__ int raw[BCAP];
    __shared__ int sorted[BCAP];
    __shared__ int dcnt[128], doff[128], dcur[128];
    int b = blockIdx.x;
    int t = threadIdx.x;
    int cnt = bcur[b];
    if (cnt > BCAP) cnt = BCAP;
    if (t < 128) dcnt[t] = 0;
    __syncthreads();
    for (int i = t; i < cnt; i += 512) {
        int e = srcBuck[b * BCAP + i];
        raw[i] = e;
        atomicAdd(&dcnt[e >> 17], 1);
    }
    __syncthreads();
    if (t < 128) doff[t] = dcnt[t];
    __syncthreads();
    for (int d = 1; d < 128; d <<= 1) {
        int add = 0;
        if (t < 128 && t >= d) add = doff[t - d];
        __syncthreads();
        if (t < 128) doff[t] += add;
        __syncthreads();
    }
    if (t < 128) {
        doff[t] -= dcnt[t];
        dcur[t] = 0;
    }
    __syncthreads();
    for (int i = t; i < cnt; i += 512) {
        int e = raw[i];
        int d = e >> 17;
        int r = atomicAdd(&dcur[d], 1);
        sorted[doff[d] + r] = e & 0x1FFFF;
    }
    __syncthreads();
    for (int i = t; i < cnt; i += 512) srcBuck[b * BCAP + i] = sorted[i];
    if (t < 128) {
        doffG[(b << 7) + t] = doff[t];
        dcntG[(b << 7) + t] = dcnt[t];
        int n = (b << 7) + t;
        if (n < N_NODES) dinv[n] = rsqrtf((float)(dcnt[t] + 1));
    }
}

// ---------------- fp8 aggregation v2: 2 blocks/bucket (dest-split halves) ----------------
// R13: FETCH 86MB (fp8 win confirmed) but dur 119us -- VALU/occupancy-bound (782 blocks =
// 3/CU, 7-op dequant chain). Fix: (1) 1564 blocks, dest-halves per bucket (srcBuck is
// dest-sorted -> contiguous index range per half; each 8-lane group owns ONE dest);
// (2) bias-folded dequant: dq = uasf((dw<<k & 0x07F00000)|(dw<<k' & 0x80000000)), scale
// carries 2^120 -> ~4-5 VALU/value, zero-check free (E=0,M=0 -> +-0).
template <bool SRC1>
__global__ __launch_bounds__(512) void aggf8_kernel(const unsigned char* __restrict__ IN8,
                                                    unsigned short* __restrict__ OUT16,
                                                    const int* __restrict__ srcBuck,
                                                    const int* __restrict__ doffG,
                                                    const int* __restrict__ dcntG,
                                                    const float* __restrict__ dinv) {
    __shared__ int sIdx[BCAP];
    __shared__ int sdoff[128], sdcnt[128];
    int t = threadIdx.x;
    int b = blockIdx.x >> 1;
    int h = blockIdx.x & 1;
    if (t < 128) {
        sdoff[t] = doffG[(b << 7) + t];
        sdcnt[t] = dcntG[(b << 7) + t];
    }
    __syncthreads();
    int start = h ? sdoff[64] : 0;
    int end = h ? (sdoff[127] + sdcnt[127]) : sdoff[64];
    for (int i = start + t; i < end; i += 512) sIdx[i - start] = srcBuck[b * BCAP + i];
    __syncthreads();

    int g8 = t >> 3;             // 64 groups of 8 lanes; group owns dest d = h*64 + g8
    int boff = (t & 7) << 4;     // 16 features (bytes) per lane within the 128B row
    int d = (h << 6) + g8;
    int n = (b << 7) + d;
    if (n >= N_NODES) return;
    float dn = dinv[n];
    float a[16];
#pragma unroll
    for (int i = 0; i < 16; i++) a[i] = 0.f;
    {
        uint4 u = *(const uint4*)(IN8 + (size_t)n * 128 + boff);
        float fs = SRC1 ? dn * EXPFIX : EXPFIX;
        DQ16(u, fs);
    }
    int o = sdoff[d] - start;
    int k = sdcnt[d];
    int j = 0;
    for (; j + 8 <= k; j += 8) {
        int s0 = sIdx[o + j + 0], s1 = sIdx[o + j + 1];
        int s2 = sIdx[o + j + 2], s3 = sIdx[o + j + 3];
        int s4 = sIdx[o + j + 4], s5 = sIdx[o + j + 5];
        int s6 = sIdx[o + j + 6], s7 = sIdx[o + j + 7];
        uint4 u0 = *(const uint4*)(IN8 + (size_t)s0 * 128 + boff);
        uint4 u1 = *(const uint4*)(IN8 + (size_t)s1 * 128 + boff);
        uint4 u2 = *(const uint4*)(IN8 + (size_t)s2 * 128 + boff);
        uint4 u3 = *(const uint4*)(IN8 + (size_t)s3 * 128 + boff);
        uint4 u4 = *(const uint4*)(IN8 + (size_t)s4 * 128 + boff);
        uint4 u5 = *(const uint4*)(IN8 + (size_t)s5 * 128 + boff);
        uint4 u6 = *(const uint4*)(IN8 + (size_t)s6 * 128 + boff);
        uint4 u7 = *(const uint4*)(IN8 + (size_t)s7 * 128 + boff);
        if (SRC1) {
            float f0 = dinv[s0] * EXPFIX, f1 = dinv[s1] * EXPFIX;
            float f2 = dinv[s2] * EXPFIX, f3 = dinv[s3] * EXPFIX;
            float f4 = dinv[s4] * EXPFIX, f5 = dinv[s5] * EXPFIX;
            float f6 = dinv[s6] * EXPFIX, f7 = dinv[s7] * EXPFIX;
            DQ16(u0, f0);
            DQ16(u1, f1);
            DQ16(u2, f2);
            DQ16(u3, f3);
            DQ16(u4, f4);
            DQ16(u5, f5);
            DQ16(u6, f6);
            DQ16(u7, f7);
        } else {
            DQ16(u0, EXPFIX);
            DQ16(u1, EXPFIX);
            DQ16(u2, EXPFIX);
            DQ16(u3, EXPFIX);
            DQ16(u4, EXPFIX);
            DQ16(u5, EXPFIX);
            DQ16(u6, EXPFIX);
            DQ16(u7, EXPFIX);
        }
    }
    for (; j + 4 <= k; j += 4) {
        int s0 = sIdx[o + j + 0], s1 = sIdx[o + j + 1];
        int s2 = sIdx[o + j + 2], s3 = sIdx[o + j + 3];
        uint4 u0 = *(const uint4*)(IN8 + (size_t)s0 * 128 + boff);
        uint4 u1 = *(const uint4*)(IN8 + (size_t)s1 * 128 + boff);
        uint4 u2 = *(const uint4*)(IN8 + (size_t)s2 * 128 + boff);
        uint4 u3 = *(const uint4*)(IN8 + (size_t)s3 * 128 + boff);
        if (SRC1) {
            float f0 = dinv[s0] * EXPFIX, f1 = dinv[s1] * EXPFIX;
            float f2 = dinv[s2] * EXPFIX, f3 = dinv[s3] * EXPFIX;
            DQ16(u0, f0);
            DQ16(u1, f1);
            DQ16(u2, f2);
            DQ16(u3, f3);
        } else {
            DQ16(u0, EXPFIX);
            DQ16(u1, EXPFIX);
            DQ16(u2, EXPFIX);
            DQ16(u3, EXPFIX);
        }
    }
    for (; j < k; j++) {
        int s0 = sIdx[o + j];
        uint4 u0 = *(const uint4*)(IN8 + (size_t)s0 * 128 + boff);
        if (SRC1) {
            float f0 = dinv[s0] * EXPFIX;
            DQ16(u0, f0);
        } else {
            DQ16(u0, EXPFIX);
        }
    }
    // write 16 bf16 (32B) at natural feature order for the MFMA A-operand
    uint4 p0, p1;
    p0.x = f2bu(a[0] * dn) | (f2bu(a[1] * dn) << 16);
    p0.y = f2bu(a[2] * dn) | (f2bu(a[3] * dn) << 16);
    p0.z = f2bu(a[4] * dn) | (f2bu(a[5] * dn) << 16);
    p0.w = f2bu(a[6] * dn) | (f2bu(a[7] * dn) << 16);
    p1.x = f2bu(a[8] * dn) | (f2bu(a[9] * dn) << 16);
    p1.y = f2bu(a[10] * dn) | (f2bu(a[11] * dn) << 16);
    p1.z = f2bu(a[12] * dn) | (f2bu(a[13] * dn) << 16);
    p1.w = f2bu(a[14] * dn) | (f2bu(a[15] * dn) << 16);
    unsigned short* wp = OUT16 + (size_t)n * 128 + boff;
    *(uint4*)wp = p0;
    *(uint4*)(wp + 8) = p1;
}

// ---------------- MFMA GEMM; mode1 packs h1 as fp8 (halves layer-2 gather array) ----------
__global__ __launch_bounds__(256) void gemm_mfma_kernel(
    const unsigned short* __restrict__ A16, const unsigned short* __restrict__ Wt,
    unsigned char* __restrict__ outB8, void* __restrict__ out,
    const float* __restrict__ params, const float* __restrict__ dinv, int mode,
    const void* __restrict__ x) {
    __shared__ float sF1[128], sF2[128];
    __shared__ int sflag;
    int t = threadIdx.x;
    int isf = detect_isf(x, t, &sflag);
    if (t < 128) {
        if (mode) {
            sF1[t] = params[PSC + t];
            sF2[t] = params[POF + t];
        } else {
            sF1[t] = params[PFB2 + t];
        }
    }
    __syncthreads();
    int wave = t >> 6, lane = t & 63, m16 = lane & 15, quad = lane >> 4;
    int rowbase = blockIdx.x * 64 + wave * 16;
    int rA = rowbase + m16;
    if (rA >= N_NODES) rA = N_NODES - 1;
    const size_t abase = (size_t)rA * 128 + (quad << 3);

    f32x4 acc[8];
#pragma unroll
    for (int ct = 0; ct < 8; ct++) acc[ct] = (f32x4){0.f, 0.f, 0.f, 0.f};
#pragma unroll
    for (int kk = 0; kk < 4; kk++) {
        bf16x8 af = *(const bf16x8*)(A16 + abase + kk * 32);
#pragma unroll
        for (int ct = 0; ct < 8; ct++) {
            bf16x8 bfr = *(const bf16x8*)(Wt + (size_t)((ct * 16 + m16) * 128) + kk * 32 + (quad << 3));
            acc[ct] = __builtin_amdgcn_mfma_f32_16x16x32_bf16(af, bfr, acc[ct], 0, 0, 0);
        }
    }

    int r0 = rowbase + quad * 4;
    if (mode) {
        float sc[8], of[8];
#pragma unroll
        for (int ct = 0; ct < 8; ct++) {
            sc[ct] = sF1[ct * 16 + m16];
            of[ct] = sF2[ct * 16 + m16];
        }
#pragma unroll
        for (int reg = 0; reg < 4; reg++) {
            int gr = r0 + reg;
            if (gr >= N_NODES) continue;
            float dn = dinv[gr];
            float vv[8];
#pragma unroll
            for (int ct = 0; ct < 8; ct++)
                vv[ct] = fmaxf(acc[ct][reg] * sc[ct] + of[ct], 0.f) * dn;
            unsigned lo = q8(vv[0]) | (q8(vv[1]) << 8) | (q8(vv[2]) << 16) | (q8(vv[3]) << 24);
            unsigned hi = q8(vv[4]) | (q8(vv[5]) << 8) | (q8(vv[6]) << 16) | (q8(vv[7]) << 24);
            *(uint2*)(outB8 + (size_t)gr * 128 + (m16 << 3)) = make_uint2(lo, hi);
        }
    } else {
        const size_t OFF_SIM = (size_t)N_NODES * OUT_C;
        const size_t OFF_HOM = OFF_SIM + (size_t)N_NODES * NUM_CLASSES;
        const size_t OFF_ENT = OFF_HOM + (size_t)N_NODES;
        float* outf = (float*)out;
        bf16* outb = (bf16*)out;
        float fb[8];
#pragma unroll
        for (int ct = 0; ct < 8; ct++) fb[ct] = sF1[ct * 16 + m16];
#define STORE_OUT(idx, v)                        \
    do {                                         \
        if (isf) outf[(idx)] = (v);              \
        else outb[(idx)] = __float2bfloat16(v);  \
    } while (0)
#pragma unroll
        for (int reg = 0; reg < 4; reg++) {
            int gr = r0 + reg;
            bool vrow = (gr < N_NODES);
            float v[8];
#pragma unroll
            for (int ct = 0; ct < 8; ct++) v[ct] = acc[ct][reg] + fb[ct];
            float m = fmaxf(fmaxf(v[0], v[1]), fmaxf(v[2], v[3]));
            m = fmaxf(m, __shfl_xor(m, 1));
            m = fmaxf(m, __shfl_xor(m, 2));
            m = fmaxf(m, __shfl_xor(m, 4));
            m = fmaxf(m, __shfl_xor(m, 8));
            float S = __expf(v[0] - m) + __expf(v[1] - m) + __expf(v[2] - m) + __expf(v[3] - m);
            S += __shfl_xor(S, 1);
            S += __shfl_xor(S, 2);
            S += __shfl_xor(S, 4);
            S += __shfl_xor(S, 8);
            float lS = m + __logf(S);
            if (vrow) {
#pragma unroll
                for (int ct = 0; ct < 4; ct++)
                    STORE_OUT((size_t)gr * OUT_C + ct * 16 + m16, v[ct] - lS);
            }
            bool has6 = (m16 < 8);
            float s4 = v[4], s5 = v[5], s6 = has6 ? v[6] : -INFINITY;
            float m2 = fmaxf(fmaxf(s4, s5), s6);
            m2 = fmaxf(m2, __shfl_xor(m2, 1));
            m2 = fmaxf(m2, __shfl_xor(m2, 2));
            m2 = fmaxf(m2, __shfl_xor(m2, 4));
            m2 = fmaxf(m2, __shfl_xor(m2, 8));
            float e4 = __expf(s4 - m2), e5 = __expf(s5 - m2), e6 = has6 ? __expf(s6 - m2) : 0.f;
            float S2 = e4 + e5 + e6;
            S2 += __shfl_xor(S2, 1);
            S2 += __shfl_xor(S2, 2);
            S2 += __shfl_xor(S2, 4);
            S2 += __shfl_xor(S2, 8);
            float rS2 = 1.f / S2;
            if (vrow) {
                STORE_OUT(OFF_SIM + (size_t)gr * NUM_CLASSES + m16, e4 * rS2);
                STORE_OUT(OFF_SIM + (size_t)gr * NUM_CLASSES + 16 + m16, e5 * rS2);
                if (has6) STORE_OUT(OFF_SIM + (size_t)gr * NUM_CLASSES + 32 + m16, e6 * rS2);
                if (m16 == 8) STORE_OUT(OFF_HOM + gr, 1.f / (1.f + __expf(-v[6])));
                if (m16 == 9) STORE_OUT(OFF_ENT + gr, 1.f / (1.f + __expf(-v[6])));
            }
        }
#undef STORE_OUT
    }
}

// ---------------- Launch: memset + 6 kernels ----------------
extern "C" void kernel_launch(void* const* d_in, const int* in_sizes, int n_in,
                              void* d_out, int out_size, void* d_ws, size_t ws_size,
                              hipStream_t stream) {
    const void* x = d_in[0];
    const int* ei = (const int*)d_in[1];

    char* ws = (char*)d_ws;
    size_t o = 0;
    auto alloc = [&](size_t bytes) {
        size_t r = o;
        o = (o + bytes + 255) & ~(size_t)255;
        return r;
    };
    char* RA = ws + alloc((size_t)51 * 1024 * 1024);  // srcBuck + X8 + H8
    char* RB = ws + alloc((size_t)26 * 1024 * 1024);  // G16
    float* params = (float*)(ws + alloc(2048));
    unsigned short* wt = (unsigned short*)(ws + alloc(65536));
    float* dinv = (float*)(ws + alloc((size_t)N_NODES * 4));
    int* doffG = (int*)(ws + alloc((size_t)NBUCK * 128 * 4));
    int* dcntG = (int*)(ws + alloc((size_t)NBUCK * 128 * 4));
    int* bcur = (int*)(ws + alloc((size_t)(NBUCK + 8) * 4));

    int* srcBuck = (int*)RA;                                        // 12.81 MB
    unsigned char* X8 = (unsigned char*)(RA + 13u * 1024 * 1024);   // 12.8 MB (fp8 x)
    unsigned char* H8 = (unsigned char*)(RA + 26u * 1024 * 1024);   // 12.8 MB (fp8 h1)
    unsigned short* G16 = (unsigned short*)RB;                      // 25.6 MB (g, bf16)

    hipMemsetAsync(bcur, 0, (size_t)(NBUCK + 8) * 4, stream);

    ParamSegs segs;
    const int srcIdx[16] = {2, 3, 4, 5, 6, 7, 8, 9, 10, 11, 12, 13, 14, 15, 16, 17};
    for (int k = 0; k < 16; k++) {
        segs.src[k] = d_in[srcIdx[k]];
        segs.dst[k] = 0;
    }

    prep_kernel<<<PREP_CVTB + CVT8_BLOCKS, 256, 0, stream>>>(x, ei, segs, bcur, srcBuck, params,
                                                             wt, X8);
    presort_kernel<<<NBUCK, 512, 0, stream>>>(srcBuck, bcur, doffG, dcntG, dinv);

    const int gemmGrid = (N_NODES + 63) / 64;
    // layer 1: g1 = A_hat x  (fp8 gather, dinv[src] inline) -> G16 (bf16)
    aggf8_kernel<true><<<2 * NBUCK, 512, 0, stream>>>(X8, G16, srcBuck, doffG, dcntG, dinv);
    // h1 = fp8(ReLU(BN(g1 W1 + b1)) * dinv) -> H8
    gemm_mfma_kernel<<<gemmGrid, 256, 0, stream>>>(G16, wt, H8, nullptr, params, dinv, 1, x);
    // layer 2: g2 = A_hat h1 (fp8 gather, plain sum) -> G16
    aggf8_kernel<false><<<2 * NBUCK, 512, 0, stream>>>(H8, G16, srcBuck, doffG, dcntG, dinv);
    // heads
    gemm_mfma_kernel<<<gemmGrid, 256, 0, stream>>>(G16, wt + 16384, nullptr, d_out, params, dinv,
                                                   0, x);
}